// Round 7
// baseline (289.173 us; speedup 1.0000x reference)
//
#include <hip/hip_runtime.h>
#include <hip/hip_bf16.h>

// ---------------------------------------------------------------------------
// TransformerLayer on MI355X (gfx950). Round 7: m201-faithful 8-phase GEMM —
// BK=64 (2x K=32 subtiles, proven swizzle), dbuf=2, counted vmcnt(4) placed
// before phase-closing barriers, setprio around MFMA clusters, NO
// sched_barrier in the K-loop. Fused QKV, packed-tri scores, tri-truncated
// split-K PV, split-K FF2.
// ---------------------------------------------------------------------------

typedef __attribute__((ext_vector_type(4))) float  f32x4;
typedef __attribute__((ext_vector_type(8))) short  bf16x8;
typedef __attribute__((ext_vector_type(4))) unsigned short us4;
typedef __attribute__((ext_vector_type(8))) unsigned short us8;

#define DEVINL __device__ __forceinline__

static constexpr int S   = 4096;
static constexpr int DM  = 1024;
static constexpr int DI  = 4096;

DEVINL unsigned short f2bf(float f) {
  union { float f; unsigned u; } v; v.f = f;
  unsigned r = v.u + 0x7fffu + ((v.u >> 16) & 1u);   // RNE
  return (unsigned short)(r >> 16);
}

DEVINL void gld_lds16(const unsigned short* g, unsigned short* l) {
  __builtin_amdgcn_global_load_lds(
      (const __attribute__((address_space(1))) void*)g,
      (__attribute__((address_space(3))) void*)l,
      16, 0, 0);
}

// ---------------------------------------------------------------------------
__global__ void cvt_f32_bf16(const float* __restrict__ in,
                             unsigned short* __restrict__ out, long n) {
  long i = ((long)blockIdx.x * 256 + threadIdx.x) * 8;
  if (i >= n) return;
  f32x4 a = *(const f32x4*)(in + i);
  f32x4 b = *(const f32x4*)(in + i + 4);
  us8 o;
  o[0] = f2bf(a[0]); o[1] = f2bf(a[1]); o[2] = f2bf(a[2]); o[3] = f2bf(a[3]);
  o[4] = f2bf(b[0]); o[5] = f2bf(b[1]); o[6] = f2bf(b[2]); o[7] = f2bf(b[3]);
  *(us8*)(out + i) = o;
}

// fp32 [R][C] -> bf16 [C][R]
__global__ void transpose_cvt(const float* __restrict__ in,
                              unsigned short* __restrict__ out, int R, int C) {
  __shared__ float tile[32][33];
  const int bx = blockIdx.x * 32, by = blockIdx.y * 32;
  const int tx = threadIdx.x, ty = threadIdx.y;
  #pragma unroll
  for (int j = 0; j < 4; ++j) {
    int r = ty + j * 8;
    tile[r][tx] = in[(size_t)(by + r) * C + bx + tx];
  }
  __syncthreads();
  #pragma unroll
  for (int j = 0; j < 4; ++j) {
    int r = ty + j * 8;
    out[(size_t)(bx + r) * R + by + tx] = f2bf(tile[tx][r]);
  }
}

// bf16 [R][C] (row stride ld) -> out[c*ldo + r]
__global__ void transpose_bf16(const unsigned short* __restrict__ in, int ld,
                               unsigned short* __restrict__ out, int ldo) {
  __shared__ unsigned short tile[32][33];
  const int bx = blockIdx.x * 32, by = blockIdx.y * 32;
  const int tx = threadIdx.x, ty = threadIdx.y;
  #pragma unroll
  for (int j = 0; j < 4; ++j) {
    int r = ty + j * 8;
    tile[r][tx] = in[(size_t)(by + r) * ld + bx + tx];
  }
  __syncthreads();
  #pragma unroll
  for (int j = 0; j < 4; ++j) {
    int r = ty + j * 8;
    out[(size_t)(bx + r) * ldo + by + tx] = tile[tx][r];
  }
}

// ---------------------------------------------------------------------------
// 256x256 tile, BK=64 (2x K32 subtiles), 512 thr (8 waves, 2Mx4N), dbuf=2
// (128 KB LDS), 4 phases/K-tile, counted vmcnt(4) before phase-closing
// barriers. C = A[M,K](lda) @ Bt[N,K](ldb)^T.
// LDS layout: [buf][part][256][32] bf16, part: 0=A-k0 1=B-k0 2=A-k1 3=B-k1.
// ---------------------------------------------------------------------------
enum { EPI_QKV = 0, EPI_SC = 2, EPI_FF1 = 4, EPI_PART = 6 };

#define VM_WAIT4 asm volatile("s_waitcnt vmcnt(4)" ::: "memory")
#define VM_WAIT0 asm volatile("s_waitcnt vmcnt(0)" ::: "memory")

template <int EPI, bool TRI_PACK, bool TRI_TRUNC>
__launch_bounds__(512, 2)
__global__ void gemm8(const unsigned short* __restrict__ A,
                      const unsigned short* __restrict__ Bt,
                      int M, int N, int K, int lda, int ldb, int kChunk,
                      const float* __restrict__ bias,
                      float* __restrict__ Cf,
                      unsigned short* __restrict__ Cb,
                      float scale) {
  int bm, bn;
  if (TRI_PACK) {
    int t = blockIdx.x;
    bm = (int)((sqrtf(8.f * (float)t + 1.f) - 1.f) * 0.5f);
    while ((bm + 1) * (bm + 2) / 2 <= t) ++bm;
    while (bm * (bm + 1) / 2 > t) --bm;
    bn = t - bm * (bm + 1) / 2;
  } else { bm = blockIdx.y; bn = blockIdx.x; }
  const int bm0 = bm * 256, bn0 = bn * 256;

  const int kbeg = blockIdx.z * kChunk;
  int kend = min(K, kbeg + kChunk);
  if (TRI_TRUNC) kend = min(kend, bm0 + 256);
  const int len = kend - kbeg;
  const int NT = (len > 0) ? (len >> 6) : 0;   // BK=64 tiles

  __shared__ __align__(16) unsigned short lds[2 * 4 * 8192];  // 128 KB

  const int tid  = threadIdx.x;
  const int lane = tid & 63;
  const int w    = tid >> 6;                  // wave 0..7
  const int wr   = w >> 2, wc = w & 3;        // 2 x 4 wave grid
  const int fr   = lane & 15, fq = lane >> 4;

  f32x4 acc[8][4] = {};

  // ---- staging (global source carries the inverse swizzle) ----
  const int tq = tid >> 2;                               // row 0..127
  const int swcolE = ((tid & 3) * 8) ^ ((tq & 6) << 2);  // swizzled col in K32
  const unsigned short* gA = A  + (size_t)(bm0 + tq) * lda + kbeg + swcolE;
  const unsigned short* gB = Bt + (size_t)(bn0 + tq) * ldb + kbeg + swcolE;
  const size_t aH = (size_t)128 * lda, bH = (size_t)128 * ldb;

  auto dstp = [&](int buf, int part, int h) {
    return (unsigned short*)lds + buf * 32768 + part * 8192 + h * 4096 + w * 512;
  };
  auto stA = [&](int buf, int t_, int ks) {   // 2 loads: A rows 0-127, 128-255
    const size_t go = (size_t)t_ * 64 + ks * 32;
    gld_lds16(gA + go,      dstp(buf, ks ? 2 : 0, 0));
    gld_lds16(gA + aH + go, dstp(buf, ks ? 2 : 0, 1));
  };
  auto stB = [&](int buf, int t_, int ks) {
    const size_t go = (size_t)t_ * 64 + ks * 32;
    gld_lds16(gB + go,      dstp(buf, ks ? 3 : 1, 0));
    gld_lds16(gB + bH + go, dstp(buf, ks ? 3 : 1, 1));
  };

  // ---- fragment reads (swizzled) ----
  const int frSw = (fq * 8) ^ ((fr & 6) << 2);
  auto rdA = [&](int buf, int mi, int ks) {
    return *(const bf16x8*)((const unsigned short*)lds + buf * 32768 +
                            (ks ? 2 : 0) * 8192 + (wr * 128 + mi * 16 + fr) * 32 + frSw);
  };
  auto rdB = [&](int buf, int ni, int ks) {
    return *(const bf16x8*)((const unsigned short*)lds + buf * 32768 +
                            (ks ? 3 : 1) * 8192 + (wc * 64 + ni * 16 + fr) * 32 + frSw);
  };

  if (NT > 0) {
    // prologue: stage tile 0 fully (order: A-k0, B-k0, A-k1, B-k1 = 8 loads)
    stA(0, 0, 0); stB(0, 0, 0); stA(0, 0, 1); stB(0, 0, 1);
    VM_WAIT4;                                  // drain k0 group; k1 in flight
    __builtin_amdgcn_s_barrier();

    for (int t = 0; t < NT; ++t) {
      const int cur = t & 1, nxt = cur ^ 1;
      const bool pf = (t + 1 < NT);
      bf16x8 a[8], p, q;

      // ---- P0: ks0, ni 0-1 ----
      #pragma unroll
      for (int mi = 0; mi < 8; ++mi) a[mi] = rdA(cur, mi, 0);
      p = rdB(cur, 0, 0); q = rdB(cur, 1, 0);
      if (pf) stA(nxt, t + 1, 0);
      __builtin_amdgcn_s_barrier();
      __builtin_amdgcn_s_setprio(1);
      #pragma unroll
      for (int mi = 0; mi < 8; ++mi) {
        acc[mi][0] = __builtin_amdgcn_mfma_f32_16x16x32_bf16(a[mi], p, acc[mi][0], 0, 0, 0);
        acc[mi][1] = __builtin_amdgcn_mfma_f32_16x16x32_bf16(a[mi], q, acc[mi][1], 0, 0, 0);
      }
      __builtin_amdgcn_s_setprio(0);
      __builtin_amdgcn_s_barrier();

      // ---- P1: ks0, ni 2-3 (A held in regs) ----
      p = rdB(cur, 2, 0); q = rdB(cur, 3, 0);
      if (pf) stB(nxt, t + 1, 0);
      __builtin_amdgcn_s_barrier();
      __builtin_amdgcn_s_setprio(1);
      #pragma unroll
      for (int mi = 0; mi < 8; ++mi) {
        acc[mi][2] = __builtin_amdgcn_mfma_f32_16x16x32_bf16(a[mi], p, acc[mi][2], 0, 0, 0);
        acc[mi][3] = __builtin_amdgcn_mfma_f32_16x16x32_bf16(a[mi], q, acc[mi][3], 0, 0, 0);
      }
      __builtin_amdgcn_s_setprio(0);
      if (pf) { VM_WAIT4; } else { VM_WAIT0; }   // drain this tile's k1 group
      __builtin_amdgcn_s_barrier();

      // ---- P2: ks1, ni 0-1 ----
      #pragma unroll
      for (int mi = 0; mi < 8; ++mi) a[mi] = rdA(cur, mi, 1);
      p = rdB(cur, 0, 1); q = rdB(cur, 1, 1);
      if (pf) stA(nxt, t + 1, 1);
      __builtin_amdgcn_s_barrier();
      __builtin_amdgcn_s_setprio(1);
      #pragma unroll
      for (int mi = 0; mi < 8; ++mi) {
        acc[mi][0] = __builtin_amdgcn_mfma_f32_16x16x32_bf16(a[mi], p, acc[mi][0], 0, 0, 0);
        acc[mi][1] = __builtin_amdgcn_mfma_f32_16x16x32_bf16(a[mi], q, acc[mi][1], 0, 0, 0);
      }
      __builtin_amdgcn_s_setprio(0);
      __builtin_amdgcn_s_barrier();

      // ---- P3: ks1, ni 2-3 ----
      p = rdB(cur, 2, 1); q = rdB(cur, 3, 1);
      if (pf) stB(nxt, t + 1, 1);
      __builtin_amdgcn_s_barrier();
      __builtin_amdgcn_s_setprio(1);
      #pragma unroll
      for (int mi = 0; mi < 8; ++mi) {
        acc[mi][2] = __builtin_amdgcn_mfma_f32_16x16x32_bf16(a[mi], p, acc[mi][2], 0, 0, 0);
        acc[mi][3] = __builtin_amdgcn_mfma_f32_16x16x32_bf16(a[mi], q, acc[mi][3], 0, 0, 0);
      }
      __builtin_amdgcn_s_setprio(0);
      if (pf) { VM_WAIT4; }                      // drain next tile's k0 group
      __builtin_amdgcn_s_barrier();
    }
  }

  // ---- epilogue: C/D layout col = lane&15, row = (lane>>4)*4 + reg ----
  const int row0 = bm0 + wr * 128 + fq * 4;
  const int col0 = bn0 + wc * 64 + fr;
  const size_t zoff = (EPI == EPI_PART) ? (size_t)blockIdx.z * M * N : 0;
  #pragma unroll
  for (int ni = 0; ni < 4; ++ni) {
    const int col = col0 + ni * 16;
    float bval = 0.f;
    if (EPI == EPI_QKV || EPI == EPI_FF1) bval = bias[col];
    #pragma unroll
    for (int mi = 0; mi < 8; ++mi) {
      #pragma unroll
      for (int j = 0; j < 4; ++j) {
        const int row = row0 + mi * 16 + j;
        const size_t idx = zoff + (size_t)row * N + col;
        const float c = acc[mi][ni][j];
        if (EPI == EPI_QKV) {
          Cb[idx] = f2bf(c + bval);
        } else if (EPI == EPI_SC) {
          Cf[idx] = c * scale;
        } else if (EPI == EPI_FF1) {
          const float r = c + bval;
          Cb[idx] = f2bf(r > 0.f ? r : 0.f);
        } else {  // EPI_PART
          Cf[idx] = c;
        }
      }
    }
  }
}

// ---------------------------------------------------------------------------
// out = sum_z P[z] + res (+bias). FINAL=false: write fp32 h + bf16 hb.
// ---------------------------------------------------------------------------
template <bool FINAL, int Z>
__global__ void reduce_k(const float* __restrict__ P,
                         const float* __restrict__ res,
                         const float* __restrict__ bias,
                         float* __restrict__ outf,
                         unsigned short* __restrict__ outb, long n) {
  long i = ((long)blockIdx.x * 256 + threadIdx.x) * 4;
  if (i >= n) return;
  f32x4 a = *(const f32x4*)(P + i);
  #pragma unroll
  for (int z = 1; z < Z; ++z) {
    f32x4 b = *(const f32x4*)(P + (size_t)z * n + i);
    #pragma unroll
    for (int j = 0; j < 4; ++j) a[j] += b[j];
  }
  f32x4 r = *(const f32x4*)(res + i);
  if (FINAL) {
    f32x4 bb = *(const f32x4*)(bias + (i & (DM - 1)));
    f32x4 o;
    #pragma unroll
    for (int j = 0; j < 4; ++j) o[j] = a[j] + r[j] + bb[j];
    *(f32x4*)(outf + i) = o;
  } else {
    f32x4 o; us4 ob;
    #pragma unroll
    for (int j = 0; j < 4; ++j) { o[j] = a[j] + r[j]; ob[j] = f2bf(o[j]); }
    *(f32x4*)(outf + i) = o;
    *(us4*)(outb + i) = ob;
  }
}

// ---------------------------------------------------------------------------
__global__ void softmax_rows(float* __restrict__ sc,
                             unsigned short* __restrict__ attnb) {
  const int m = blockIdx.x;
  const int tid = threadIdx.x;
  const int valid = m + 1;
  float* rowf = sc + (size_t)m * S;
  unsigned short* rowb = attnb + (size_t)m * S;

  f32x4 v[4];
  float lmax = -1e30f;
  #pragma unroll
  for (int i = 0; i < 4; ++i) {
    if (i * 1024 <= m) {
      const int idx = tid * 4 + i * 1024;
      v[i] = *(const f32x4*)(rowf + idx);
      #pragma unroll
      for (int j = 0; j < 4; ++j)
        if (idx + j < valid) lmax = fmaxf(lmax, v[i][j]);
    }
  }
  #pragma unroll
  for (int off = 32; off > 0; off >>= 1)
    lmax = fmaxf(lmax, __shfl_xor(lmax, off, 64));

  __shared__ float red[8];
  if ((tid & 63) == 0) red[tid >> 6] = lmax;
  __syncthreads();
  lmax = fmaxf(fmaxf(red[0], red[1]), fmaxf(red[2], red[3]));

  f32x4 e[4];
  float lsum = 0.f;
  #pragma unroll
  for (int i = 0; i < 4; ++i) {
    const int idx = tid * 4 + i * 1024;
    #pragma unroll
    for (int j = 0; j < 4; ++j) e[i][j] = 0.f;
    if (i * 1024 <= m) {
      #pragma unroll
      for (int j = 0; j < 4; ++j) {
        const float ev = (idx + j < valid) ? __expf(v[i][j] - lmax) : 0.f;
        e[i][j] = ev;
        lsum += ev;
      }
    }
  }
  #pragma unroll
  for (int off = 32; off > 0; off >>= 1)
    lsum += __shfl_xor(lsum, off, 64);
  if ((tid & 63) == 0) red[4 + (tid >> 6)] = lsum;
  __syncthreads();
  const float tsum = red[4] + red[5] + red[6] + red[7];
  const float inv = 1.0f / tsum;

  #pragma unroll
  for (int i = 0; i < 4; ++i) {
    const int idx = tid * 4 + i * 1024;
    f32x4 o; us4 ob;
    #pragma unroll
    for (int j = 0; j < 4; ++j) {
      const float t = e[i][j] * inv;
      o[j] = t;
      ob[j] = f2bf(t);
    }
    *(f32x4*)(rowf + idx) = o;
    *(us4*)(rowb + idx) = ob;
  }
}

// ---------------------------------------------------------------------------
extern "C" void kernel_launch(void* const* d_in, const int* in_sizes, int n_in,
                              void* d_out, int out_size, void* d_ws, size_t ws_size,
                              hipStream_t stream) {
  const float* x  = (const float*)d_in[0];
  const float* Wq = (const float*)d_in[1];
  const float* bq = (const float*)d_in[2];
  const float* Wk = (const float*)d_in[3];
  const float* bk = (const float*)d_in[4];
  const float* Wv = (const float*)d_in[5];
  const float* bv = (const float*)d_in[6];
  const float* W1 = (const float*)d_in[7];
  const float* b1 = (const float*)d_in[8];
  const float* W2 = (const float*)d_in[9];
  const float* b2 = (const float*)d_in[10];
  (void)in_sizes; (void)n_in; (void)out_size;

  float* outp  = (float*)d_out;                       // [S, DM]
  float* attnf = (float*)d_out + (size_t)S * DM;      // [S, S]

  const size_t MB = 1ull << 20;
  char* ws = (char*)d_ws;
  unsigned short* W2t   = (unsigned short*)(ws + 0 * MB);    // [DM,DI]  1->7
  unsigned short* W1t   = (unsigned short*)(ws + 8 * MB);    // [DI,DM]  1->6
  float*          h     = (float*)(ws + 16 * MB);            // [S,DM]   5->7
  unsigned short* hb    = (unsigned short*)(ws + 32 * MB);   // [S,DM]   5->6
  unsigned short* vt    = (unsigned short*)(ws + 40 * MB);   // [DM,S]   2->5
  unsigned short* attnb = (unsigned short*)(ws + 48 * MB);   // [S,S]    4->5
  unsigned short* qkv   = (unsigned short*)(ws + 80 * MB);   // [S,3072] 2->3
  unsigned short* xb    = (unsigned short*)(ws + 104 * MB);  // [S,DM]   1->2
  unsigned short* Wqkvt = (unsigned short*)(ws + 112 * MB);  // [3072,DM]1->2
  float*          bqkv  = (float*)(ws + 118 * MB);           // [3072]   1->2
  unsigned short* ff1b  = (unsigned short*)(ws + 40 * MB);   // [S,DI]   6->7
  float*          Ppv   = (float*)(ws + 80 * MB);            // [z][S,DM] ph5
  float*          Pff   = (float*)(ws + 72 * MB);            // [z][S,DM] ph7

  const bool big = ws_size >= 145 * MB;   // z=4 partials fit?

  // --- phase 1: converts / transposes / bias concat
  cvt_f32_bf16<<<dim3((S * DM) / 2048), 256, 0, stream>>>(x, xb, (long)S * DM);
  transpose_cvt<<<dim3(DM / 32, DM / 32), dim3(32, 8), 0, stream>>>(Wq, Wqkvt, DM, DM);
  transpose_cvt<<<dim3(DM / 32, DM / 32), dim3(32, 8), 0, stream>>>(Wk, Wqkvt + (size_t)DM * DM, DM, DM);
  transpose_cvt<<<dim3(DM / 32, DM / 32), dim3(32, 8), 0, stream>>>(Wv, Wqkvt + 2 * (size_t)DM * DM, DM, DM);
  transpose_cvt<<<dim3(DI / 32, DM / 32), dim3(32, 8), 0, stream>>>(W1, W1t, DM, DI);
  transpose_cvt<<<dim3(DM / 32, DI / 32), dim3(32, 8), 0, stream>>>(W2, W2t, DI, DM);
  hipMemcpyAsync(bqkv,          bq, DM * sizeof(float), hipMemcpyDeviceToDevice, stream);
  hipMemcpyAsync(bqkv + DM,     bk, DM * sizeof(float), hipMemcpyDeviceToDevice, stream);
  hipMemcpyAsync(bqkv + 2 * DM, bv, DM * sizeof(float), hipMemcpyDeviceToDevice, stream);

  // --- phase 2: fused QKV projection, then v -> vt
  gemm8<EPI_QKV, false, false><<<dim3(3072 / 256, S / 256, 1), 512, 0, stream>>>(
      xb, Wqkvt, S, 3072, DM, DM, DM, DM, bqkv, nullptr, qkv, 1.f);
  transpose_bf16<<<dim3(DM / 32, S / 32), dim3(32, 8), 0, stream>>>(
      qkv + 2 * DM, 3072, vt, S);

  // --- phase 3: scores = q @ k^T / 32 (packed lower-tri grid, 136 blocks)
  gemm8<EPI_SC, true, false><<<dim3(136, 1, 1), 512, 0, stream>>>(
      qkv, qkv + DM, S, S, DM, 3072, 3072, DM, nullptr, attnf, nullptr, 0.03125f);

  // --- phase 4: causal softmax (fp32 in d_out) + bf16 copy
  softmax_rows<<<dim3(S), 256, 0, stream>>>(attnf, attnb);

  // --- phase 5: attended = attn @ v (tri-truncated, split-K) + reduce -> h, hb
  if (big) {
    gemm8<EPI_PART, false, true><<<dim3(DM / 256, S / 256, 4), 512, 0, stream>>>(
        attnb, vt, S, DM, S, S, S, S / 4, nullptr, Ppv, nullptr, 1.f);
    reduce_k<false, 4><<<dim3((S * DM) / 1024), 256, 0, stream>>>(
        Ppv, x, nullptr, h, hb, (long)S * DM);
  } else {
    gemm8<EPI_PART, false, true><<<dim3(DM / 256, S / 256, 2), 512, 0, stream>>>(
        attnb, vt, S, DM, S, S, S, S / 2, nullptr, Ppv, nullptr, 1.f);
    reduce_k<false, 2><<<dim3((S * DM) / 1024), 256, 0, stream>>>(
        Ppv, x, nullptr, h, hb, (long)S * DM);
  }

  // --- phase 6: ff1 = relu(h @ W1 + b1)
  gemm8<EPI_FF1, false, false><<<dim3(DI / 256, S / 256, 1), 512, 0, stream>>>(
      hb, W1t, S, DI, DM, DM, DM, DM, b1, nullptr, ff1b, 1.f);

  // --- phase 7: out = h + ff1 @ W2 + b2 (split-K) + final reduce
  if (big) {
    gemm8<EPI_PART, false, false><<<dim3(DM / 256, S / 256, 4), 512, 0, stream>>>(
        ff1b, W2t, S, DM, DI, DI, DI, DI / 4, nullptr, Pff, nullptr, 1.f);
    reduce_k<true, 4><<<dim3((S * DM) / 1024), 256, 0, stream>>>(
        Pff, h, b2, outp, nullptr, (long)S * DM);
  } else {
    gemm8<EPI_PART, false, false><<<dim3(DM / 256, S / 256, 2), 512, 0, stream>>>(
        ff1b, W2t, S, DM, DI, DI, DI, DI / 2, nullptr, Pff, nullptr, 1.f);
    reduce_k<true, 2><<<dim3((S * DM) / 1024), 256, 0, stream>>>(
        Pff, h, b2, outp, nullptr, (long)S * DM);
  }
}